// Round 14
// baseline (513.635 us; speedup 1.0000x reference)
//
#include <hip/hip_runtime.h>
#include <stdint.h>

#define RS32 0.17677669529663687f  // 1/sqrt(32)

typedef short bf16x8 __attribute__((ext_vector_type(8)));
typedef float f32x4 __attribute__((ext_vector_type(4)));

__device__ __forceinline__ ushort f2bf(float f) {
  uint32_t b = __float_as_uint(f);
  b = (b + 0x7fffu + ((b >> 16) & 1u)) >> 16;
  return (ushort)b;
}
__device__ __forceinline__ float bflo(uint32_t w) { return __uint_as_float(w << 16); }
__device__ __forceinline__ float bfhi(uint32_t w) { return __uint_as_float(w & 0xffff0000u); }
__device__ __forceinline__ float bfu(ushort s) { return __uint_as_float(((uint32_t)s) << 16); }

// ---------------- projection: direct-from-global bf16 MFMA, zero LDS ----
// dim3(NB, 8): y=0 k(->kvi), 1 v(->kvi), 2 skip(bf16), 3 q(bf16), 4..7 u-head (W=Mtb)
__launch_bounds__(256)
__global__ void proj_direct_kernel(const ushort* __restrict__ xb16,
                                   const ushort* __restrict__ Wb,   // [4][128][128] k,v,skip,q
                                   const ushort* __restrict__ Mtb,  // [4][128][128] u heads
                                   const float* __restrict__ bk, const float* __restrict__ bv,
                                   const float* __restrict__ bs, const float* __restrict__ bq,
                                   const float* __restrict__ bu,
                                   ushort* __restrict__ skipb, ushort* __restrict__ kvi,
                                   ushort* __restrict__ u, ushort* __restrict__ qb, int N)
{
  const int y = blockIdx.y;
  const ushort* Wsrc = (y < 4) ? (Wb + (size_t)y * 16384) : (Mtb + (size_t)(y - 4) * 16384);

  const int tid = threadIdx.x;
  const int nb = blockIdx.x * 128;
  const int lane = tid & 63, wv = tid >> 6;
  const int wr = (wv >> 1) * 64, wc = (wv & 1) * 64;
  const int fr = lane & 15, fq = lane >> 4;

  f32x4 acc[4][4];
#pragma unroll
  for (int m = 0; m < 4; ++m)
#pragma unroll
    for (int n = 0; n < 4; ++n) acc[m][n] = (f32x4)0.0f;

#pragma unroll
  for (int kk = 0; kk < 4; ++kk) {
    const int ko = kk * 32 + fq * 8;
    bf16x8 af[4], bf[4];
#pragma unroll
    for (int m = 0; m < 4; ++m)
      af[m] = *(const bf16x8*)(xb16 + (size_t)(nb + wr + m * 16 + fr) * 128 + ko);
#pragma unroll
    for (int n = 0; n < 4; ++n)
      bf[n] = *(const bf16x8*)(Wsrc + (size_t)(wc + n * 16 + fr) * 128 + ko);
#pragma unroll
    for (int m = 0; m < 4; ++m)
#pragma unroll
      for (int n = 0; n < 4; ++n)
        acc[m][n] = __builtin_amdgcn_mfma_f32_16x16x32_bf16(af[m], bf[n], acc[m][n], 0, 0, 0);
  }

  float bcol[4];
#pragma unroll
  for (int n = 0; n < 4; ++n) {
    const int c = wc + n * 16 + fr;
    bcol[n] = (y == 0) ? bk[c] : (y == 1) ? bv[c] : (y == 2) ? bs[c]
            : (y == 3) ? bq[c] : bu[(y - 4) * 128 + c];
  }
#pragma unroll
  for (int m = 0; m < 4; ++m) {
    const int r0 = nb + wr + m * 16 + fq * 4;
#pragma unroll
    for (int r = 0; r < 4; ++r) {
      const int gr = r0 + r;
      if (gr < N) {
#pragma unroll
        for (int n = 0; n < 4; ++n) {
          const int c = wc + n * 16 + fr;
          float o = acc[m][n][r] + bcol[n];
          if (y == 2)      skipb[(size_t)gr * 128 + c] = f2bf(o);
          else if (y == 3) qb[(size_t)gr * 128 + c] = f2bf(o);
          else if (y == 0) kvi[(size_t)gr * 256 + (c >> 2) * 8 + (c & 3)] = f2bf(o);
          else if (y == 1) kvi[(size_t)gr * 256 + (c >> 2) * 8 + 4 + (c & 3)] = f2bf(o);
          else             u[(size_t)gr * 512 + (y - 4) * 128 + c] = f2bf(o);
        }
      }
    }
  }
}

// ---------------- prep: x -> bf16 ----------------
__global__ void x2bf_kernel(const float* __restrict__ x, ushort* __restrict__ xb, int total4)
{
  int i = blockIdx.x * 256 + threadIdx.x;
  if (i < total4) {
    float4 v = ((const float4*)x)[i];
    uint2 w = make_uint2((uint32_t)f2bf(v.x) | ((uint32_t)f2bf(v.y) << 16),
                         (uint32_t)f2bf(v.z) | ((uint32_t)f2bf(v.w) << 16));
    ((uint2*)xb)[i] = w;
  }
}

// ---------------- all weight preps in one launch (segmented grid) ----------------
__global__ void prep_all_kernel(const float* __restrict__ Wk, const float* __restrict__ Wv,
                                const float* __restrict__ Ws, const float* __restrict__ Wq,
                                const float* __restrict__ Wp, const float* __restrict__ Wm,
                                const float* __restrict__ We, const float* __restrict__ bq,
                                ushort* __restrict__ Wb, ushort* __restrict__ Wpb,
                                ushort* __restrict__ Wmb, ushort* __restrict__ WeB,
                                ushort* __restrict__ Mtb, float* __restrict__ bu)
{
  int i = blockIdx.x * 256 + threadIdx.x;
  if (i < 65536) {
    int y = i >> 14, r = i & 16383;
    const float* src = (y == 0) ? Wk : (y == 1) ? Wv : (y == 2) ? Ws : Wq;
    Wb[i] = f2bf(src[r]);
    return;
  }
  i -= 65536;
  if (i < 16384) { Wpb[i] = f2bf(Wp[i]); Wmb[i] = f2bf(Wm[i]); return; }
  i -= 16384;
  if (i < 65536) {
    int c = i >> 9, j = i & 511;
    int hh = j >> 7, k2 = j & 127;
    WeB[i] = (hh == (c >> 5)) ? f2bf(We[(size_t)c * 128 + k2]) : (ushort)0;
    return;
  }
  i -= 65536;
  if (i < 65536) {
    int jp = i >> 7, d = i & 127;
    int h = jp >> 7, j = jp & 127;
    const float* wq = Wq + (size_t)(32 * h) * 128 + d;
    const float* we = We + (size_t)(32 * h) * 128 + j;
    float acc = 0.f;
#pragma unroll 8
    for (int a = 0; a < 32; ++a) acc = fmaf(wq[a * 128], we[a * 128], acc);
    Mtb[i] = f2bf(acc);
    return;
  }
  i -= 65536;
  if (i < 512) {
    int h = i >> 7, j = i & 127;
    float acc = 0.f;
    for (int a = 0; a < 32; ++a)
      acc = fmaf(bq[32 * h + a], We[(size_t)(32 * h + a) * 128 + j], acc);
    bu[i] = acc;
  }
}

// ---------------- CSR build ----------------
__global__ void deg_kernel(const int* __restrict__ ei, int* __restrict__ deg, int E)
{
  int e = blockIdx.x * 256 + threadIdx.x;
  if (e < E) atomicAdd(&deg[ei[E + e]], 1);
}

__launch_bounds__(256)
__global__ void start_kernel(const int* __restrict__ deg, int* __restrict__ offs,
                             int* __restrict__ cursor, int* __restrict__ gcount, int N)
{
  const int i = blockIdx.x * 256 + threadIdx.x;
  const int lane = threadIdx.x & 63;
  int d = (i < N) ? deg[i] : 0;
  int scan = d;
#pragma unroll
  for (int ofs = 1; ofs < 64; ofs <<= 1) {
    int t = __shfl_up(scan, ofs, 64);
    if (lane >= ofs) scan += t;
  }
  int total = __shfl(scan, 63, 64);
  int base = 0;
  if (lane == 63) base = atomicAdd(gcount, total);
  base = __shfl(base, 63, 64);
  int excl = base + scan - d;
  if (i < N) { offs[i] = excl; cursor[i] = excl; }
}

__global__ void fill_kernel(const int* __restrict__ ei, int* __restrict__ cursor,
                            int2* __restrict__ csr, int E)
{
  int e = blockIdx.x * 256 + threadIdx.x;
  if (e < E) {
    int dst = ei[E + e];
    int slot = atomicAdd(&cursor[dst], 1);
    csr[slot] = make_int2(ei[e], e);
  }
}

// ---------------- fused node-major attention: register-diet variant ----------------
// wave per node; 2 edge slots of 32 lanes; lane (p, j32) owns channels 4*j32..+3.
// No explicit prefetch rotation (compiler-scheduled loads) -> fewer VGPRs -> more waves/SIMD.
__launch_bounds__(256)
__global__ void fused_attn2_kernel(const int2* __restrict__ csr, const int* __restrict__ offs,
                                   const int* __restrict__ deg,
                                   const ushort* __restrict__ qb, const ushort* __restrict__ kvi,
                                   const ushort* __restrict__ u,
                                   const float* __restrict__ eattr,
                                   ushort* __restrict__ aggS, ushort* __restrict__ wsb, int N)
{
  const int tid = threadIdx.x;
  const int lane = tid & 63;
  const int wid = tid >> 6;
  const int p = lane >> 5;          // edge slot 0/1
  const int j32 = lane & 31;
  const int c0 = j32 * 4;           // my 4 channels
  const int h = j32 >> 3;           // head of my channels
  const int gwave = blockIdx.x * 4 + wid;
  const int nwaves = gridDim.x * 4;

  for (int n = gwave; n < N; n += nwaves) {
    const int e0 = offs[n];
    const int e1 = e0 + deg[n];

    const uint2 qp = *(const uint2*)(qb + (size_t)n * 128 + c0);
    uint2 uhp[4];
#pragma unroll
    for (int hh = 0; hh < 4; ++hh)
      uhp[hh] = *(const uint2*)(u + (size_t)n * 512 + hh * 128 + c0);

    float ws0 = 0.f, ws1 = 0.f, ws2 = 0.f, ws3 = 0.f;
    float ax[4][4];
#pragma unroll
    for (int hh = 0; hh < 4; ++hh)
#pragma unroll
      for (int j = 0; j < 4; ++j) ax[hh][j] = 0.f;
    float sm0 = 0.f, sm1 = 0.f, sm2 = 0.f, sm3 = 0.f;

    for (int sl = e0 + p; sl < e1; sl += 2) {
      const int2 se = csr[sl];
      const float4 ea = *(const float4*)(eattr + (size_t)se.y * 128 + c0);
      const uint4 kv = *(const uint4*)(kvi + (size_t)se.x * 256 + j32 * 8);

      float P0 = ea.x * bflo(uhp[0].x) + ea.y * bfhi(uhp[0].x)
               + ea.z * bflo(uhp[0].y) + ea.w * bfhi(uhp[0].y);
      float P1 = ea.x * bflo(uhp[1].x) + ea.y * bfhi(uhp[1].x)
               + ea.z * bflo(uhp[1].y) + ea.w * bfhi(uhp[1].y);
      float P2 = ea.x * bflo(uhp[2].x) + ea.y * bfhi(uhp[2].x)
               + ea.z * bflo(uhp[2].y) + ea.w * bfhi(uhp[2].y);
      float P3 = ea.x * bflo(uhp[3].x) + ea.y * bfhi(uhp[3].x)
               + ea.z * bflo(uhp[3].y) + ea.w * bfhi(uhp[3].y);
      const float qk = bflo(qp.x) * bflo(kv.x) + bfhi(qp.x) * bfhi(kv.x)
                     + bflo(qp.y) * bflo(kv.y) + bfhi(qp.y) * bfhi(kv.y);
      P0 += (h == 0) ? qk : 0.f;
      P1 += (h == 1) ? qk : 0.f;
      P2 += (h == 2) ? qk : 0.f;
      P3 += (h == 3) ? qk : 0.f;
#pragma unroll
      for (int mm = 1; mm <= 16; mm <<= 1) {
        P0 += __shfl_xor(P0, mm, 64);
        P1 += __shfl_xor(P1, mm, 64);
        P2 += __shfl_xor(P2, mm, 64);
        P3 += __shfl_xor(P3, mm, 64);
      }
      const float a0 = __expf(P0 * RS32);
      const float a1 = __expf(P1 * RS32);
      const float a2 = __expf(P2 * RS32);
      const float a3 = __expf(P3 * RS32);
      sm0 += a0; sm1 += a1; sm2 += a2; sm3 += a3;
      const float aV = (h == 0) ? a0 : (h == 1) ? a1 : (h == 2) ? a2 : a3;
      ws0 = fmaf(aV, bflo(kv.z), ws0); ws1 = fmaf(aV, bfhi(kv.z), ws1);
      ws2 = fmaf(aV, bflo(kv.w), ws2); ws3 = fmaf(aV, bfhi(kv.w), ws3);
      ax[0][0] = fmaf(a0, ea.x, ax[0][0]); ax[0][1] = fmaf(a0, ea.y, ax[0][1]);
      ax[0][2] = fmaf(a0, ea.z, ax[0][2]); ax[0][3] = fmaf(a0, ea.w, ax[0][3]);
      ax[1][0] = fmaf(a1, ea.x, ax[1][0]); ax[1][1] = fmaf(a1, ea.y, ax[1][1]);
      ax[1][2] = fmaf(a1, ea.z, ax[1][2]); ax[1][3] = fmaf(a1, ea.w, ax[1][3]);
      ax[2][0] = fmaf(a2, ea.x, ax[2][0]); ax[2][1] = fmaf(a2, ea.y, ax[2][1]);
      ax[2][2] = fmaf(a2, ea.z, ax[2][2]); ax[2][3] = fmaf(a2, ea.w, ax[2][3]);
      ax[3][0] = fmaf(a3, ea.x, ax[3][0]); ax[3][1] = fmaf(a3, ea.y, ax[3][1]);
      ax[3][2] = fmaf(a3, ea.z, ax[3][2]); ax[3][3] = fmaf(a3, ea.w, ax[3][3]);
    }

#pragma unroll
    for (int hh = 0; hh < 4; ++hh)
#pragma unroll
      for (int j = 0; j < 4; ++j) ax[hh][j] += __shfl_xor(ax[hh][j], 32, 64);
    ws0 += __shfl_xor(ws0, 32, 64); ws1 += __shfl_xor(ws1, 32, 64);
    ws2 += __shfl_xor(ws2, 32, 64); ws3 += __shfl_xor(ws3, 32, 64);
    sm0 += __shfl_xor(sm0, 32, 64); sm1 += __shfl_xor(sm1, 32, 64);
    sm2 += __shfl_xor(sm2, 32, 64); sm3 += __shfl_xor(sm3, 32, 64);

    const float iv0 = (sm0 > 0.f) ? 1.f / sm0 : 0.f;
    const float iv1 = (sm1 > 0.f) ? 1.f / sm1 : 0.f;
    const float iv2 = (sm2 > 0.f) ? 1.f / sm2 : 0.f;
    const float iv3 = (sm3 > 0.f) ? 1.f / sm3 : 0.f;

    if (p == 0) {
      const float s = (h == 0) ? iv0 : (h == 1) ? iv1 : (h == 2) ? iv2 : iv3;
      uint2 w = make_uint2(((uint32_t)f2bf(ws0 * s)) | (((uint32_t)f2bf(ws1 * s)) << 16),
                           ((uint32_t)f2bf(ws2 * s)) | (((uint32_t)f2bf(ws3 * s)) << 16));
      *(uint2*)(wsb + (size_t)n * 128 + c0) = w;
    }

    float o0[4], o1[4], s0, s1;
    if (p == 0) {
#pragma unroll
      for (int j = 0; j < 4; ++j) { o0[j] = ax[0][j]; o1[j] = ax[1][j]; }
      s0 = iv0; s1 = iv1;
    } else {
#pragma unroll
      for (int j = 0; j < 4; ++j) { o0[j] = ax[2][j]; o1[j] = ax[3][j]; }
      s0 = iv2; s1 = iv3;
    }
    uint2 w0 = make_uint2(((uint32_t)f2bf(o0[0] * s0)) | (((uint32_t)f2bf(o0[1] * s0)) << 16),
                          ((uint32_t)f2bf(o0[2] * s0)) | (((uint32_t)f2bf(o0[3] * s0)) << 16));
    uint2 w1 = make_uint2(((uint32_t)f2bf(o1[0] * s1)) | (((uint32_t)f2bf(o1[1] * s1)) << 16),
                          ((uint32_t)f2bf(o1[2] * s1)) | (((uint32_t)f2bf(o1[3] * s1)) << 16));
    *(uint2*)(aggS + (size_t)n * 512 + (p * 2) * 128 + c0) = w0;
    *(uint2*)(aggS + (size_t)n * 512 + (p * 2 + 1) * 128 + c0) = w1;
  }
}

// ---------------- fused post: attn = aggS@WeB^T + wsb; z = bf16(relu(attn+skip));
// t1 = z @ Wpb^T + bp; fused LN column stats ----------------
__launch_bounds__(256)
__global__ void fused_post_kernel(const ushort* __restrict__ aggS, const ushort* __restrict__ WeB,
                                  const ushort* __restrict__ wsb, const ushort* __restrict__ skipb,
                                  const ushort* __restrict__ Wpb, const float* __restrict__ bp,
                                  float* __restrict__ t1,
                                  float* __restrict__ sums, float* __restrict__ sumsq, int N)
{
  __shared__ ushort smem[2 * 128 * 72];   // phase1: As|Bs ; phase2: zs[128][136]
  ushort* As = smem;
  ushort* Bs = smem + 128 * 72;
  const int tid = threadIdx.x;
  const int nb = blockIdx.x * 128;
  const int lane = tid & 63, wv = tid >> 6;
  const int wr = (wv >> 1) * 64, wc = (wv & 1) * 64;
  const int fr = lane & 15, fq = lane >> 4;
  const int r = tid >> 1, cs = (tid & 1) * 32;

  f32x4 acc[4][4];
#pragma unroll
  for (int m = 0; m < 4; ++m)
#pragma unroll
    for (int n = 0; n < 4; ++n) acc[m][n] = (f32x4)0.0f;

  // phase 1: aggS @ WeB^T (K=512)
  for (int kc = 0; kc < 512; kc += 64) {
    uint4 av[4], bv[4];
    if (nb + r < N) {
      const uint4* src = (const uint4*)(aggS + (size_t)(nb + r) * 512 + kc + cs);
      av[0] = src[0]; av[1] = src[1]; av[2] = src[2]; av[3] = src[3];
    } else {
#pragma unroll
      for (int i = 0; i < 4; ++i) av[i] = make_uint4(0, 0, 0, 0);
    }
    {
      const uint4* src = (const uint4*)(WeB + (size_t)r * 512 + kc + cs);
      bv[0] = src[0]; bv[1] = src[1]; bv[2] = src[2]; bv[3] = src[3];
    }
    if (kc) __syncthreads();
#pragma unroll
    for (int i = 0; i < 4; ++i) {
      *(uint4*)&As[r * 72 + cs + i * 8] = av[i];
      *(uint4*)&Bs[r * 72 + cs + i * 8] = bv[i];
    }
    __syncthreads();

#pragma unroll
    for (int s = 0; s < 2; ++s) {
      bf16x8 ah[4], bh[4];
#pragma unroll
      for (int m = 0; m < 4; ++m)
        ah[m] = *(const bf16x8*)&As[(wr + m * 16 + fr) * 72 + s * 32 + fq * 8];
#pragma unroll
      for (int n = 0; n < 4; ++n)
        bh[n] = *(const bf16x8*)&Bs[(wc + n * 16 + fr) * 72 + s * 32 + fq * 8];
#pragma unroll
      for (int m = 0; m < 4; ++m)
#pragma unroll
        for (int n = 0; n < 4; ++n)
          acc[m][n] = __builtin_amdgcn_mfma_f32_16x16x32_bf16(ah[m], bh[n], acc[m][n], 0, 0, 0);
    }
  }
  __syncthreads();   // all waves done reading As/Bs

  // epilogue 1: z = bf16(relu(attn + ws + skip)) -> zs (aliased over smem)
  ushort* zs = smem;   // [128][136]
#pragma unroll
  for (int m = 0; m < 4; ++m) {
    const int lr0 = wr + m * 16 + fq * 4;
#pragma unroll
    for (int rr = 0; rr < 4; ++rr) {
      const int lrow = lr0 + rr;
      const int gr = nb + lrow;
#pragma unroll
      for (int n = 0; n < 4; ++n) {
        const int c = wc + n * 16 + fr;
        float o = 0.f;
        if (gr < N) {
          o = acc[m][n][rr] + bfu(wsb[(size_t)gr * 128 + c]) + bfu(skipb[(size_t)gr * 128 + c]);
          o = fmaxf(o, 0.f);
        }
        zs[lrow * 136 + c] = f2bf(o);
      }
    }
  }
  __syncthreads();

  // phase 2: t1 = zs @ Wpb^T (K=128), Wpb direct from global
  f32x4 acc2[4][4];
#pragma unroll
  for (int m = 0; m < 4; ++m)
#pragma unroll
    for (int n = 0; n < 4; ++n) acc2[m][n] = (f32x4)0.0f;
#pragma unroll
  for (int kk = 0; kk < 4; ++kk) {
    const int ko = kk * 32 + fq * 8;
    bf16x8 af[4], bf[4];
#pragma unroll
    for (int m = 0; m < 4; ++m)
      af[m] = *(const bf16x8*)&zs[(wr + m * 16 + fr) * 136 + ko];
#pragma unroll
    for (int n = 0; n < 4; ++n)
      bf[n] = *(const bf16x8*)(Wpb + (size_t)(wc + n * 16 + fr) * 128 + ko);
#pragma unroll
    for (int m = 0; m < 4; ++m)
#pragma unroll
      for (int n = 0; n < 4; ++n)
        acc2[m][n] = __builtin_amdgcn_mfma_f32_16x16x32_bf16(af[m], bf[n], acc2[m][n], 0, 0, 0);
  }

  float bcol[4];
#pragma unroll
  for (int n = 0; n < 4; ++n) bcol[n] = bp[wc + n * 16 + fr];
  float csum[4] = {0.f, 0.f, 0.f, 0.f}, csum2[4] = {0.f, 0.f, 0.f, 0.f};
#pragma unroll
  for (int m = 0; m < 4; ++m) {
    const int r0 = nb + wr + m * 16 + fq * 4;
#pragma unroll
    for (int rr = 0; rr < 4; ++rr) {
      const int gr = r0 + rr;
      if (gr < N) {
#pragma unroll
        for (int n = 0; n < 4; ++n) {
          const int c = wc + n * 16 + fr;
          float o = acc2[m][n][rr] + bcol[n];
          t1[(size_t)gr * 128 + c] = o;
          csum[n] += o; csum2[n] = fmaf(o, o, csum2[n]);
        }
      }
    }
  }
#pragma unroll
  for (int n = 0; n < 4; ++n) {
    csum[n] += __shfl_xor(csum[n], 16, 64);
    csum[n] += __shfl_xor(csum[n], 32, 64);
    csum2[n] += __shfl_xor(csum2[n], 16, 64);
    csum2[n] += __shfl_xor(csum2[n], 32, 64);
  }
  if (fq == 0) {
#pragma unroll
    for (int n = 0; n < 4; ++n) {
      atomicAdd(&sums[wc + n * 16 + fr], csum[n]);
      atomicAdd(&sumsq[wc + n * 16 + fr], csum2[n]);
    }
  }
}

__global__ void finalize_stats_kernel(const float* __restrict__ sums, const float* __restrict__ sumsq,
                                      float* __restrict__ mu, float* __restrict__ inv, int N)
{
  int c = threadIdx.x;
  float m = sums[c] / (float)N;
  float var = sumsq[c] / (float)N - m * m;
  float sd = sqrtf(fmaxf(var, 0.f));
  mu[c] = m;
  inv[c] = 1.f / (sd + 1e-5f);
}

// ---------------- out = bf16(relu((t1-mu)*inv)) @ Wmb^T + bm + x  (LN fused into A-load) ----
__launch_bounds__(256)
__global__ void out_gemm_kernel(const float* __restrict__ t1, const float* __restrict__ mu,
                                const float* __restrict__ inv,
                                const ushort* __restrict__ Wmb,
                                const float* __restrict__ bm, const float* __restrict__ x,
                                float* __restrict__ out, int N)
{
  const int tid = threadIdx.x;
  const int nb = blockIdx.x * 128;
  const int lane = tid & 63, wv = tid >> 6;
  const int wr = (wv >> 1) * 64, wc = (wv & 1) * 64;
  const int fr = lane & 15, fq = lane >> 4;

  f32x4 acc[4][4];
#pragma unroll
  for (int m = 0; m < 4; ++m)
#pragma unroll
    for (int n = 0; n < 4; ++n) acc[m][n] = (f32x4)0.0f;

#pragma unroll
  for (int kk = 0; kk < 4; ++kk) {
    const int ko = kk * 32 + fq * 8;
    const float4 m0 = *(const float4*)(mu + ko);
    const float4 m1 = *(const float4*)(mu + ko + 4);
    const float4 i0 = *(const float4*)(inv + ko);
    const float4 i1 = *(const float4*)(inv + ko + 4);
    bf16x8 af[4], bf[4];
#pragma unroll
    for (int m = 0; m < 4; ++m) {
      const int gr = nb + wr + m * 16 + fr;
      float4 v0 = make_float4(0.f, 0.f, 0.f, 0.f), v1 = v0;
      if (gr < N) {
        v0 = *(const float4*)(t1 + (size_t)gr * 128 + ko);
        v1 = *(const float4*)(t1 + (size_t)gr * 128 + ko + 4);
      }
      float z[8];
      z[0] = fmaxf((v0.x - m0.x) * i0.x, 0.f); z[1] = fmaxf((v0.y - m0.y) * i0.y, 0.f);
      z[2] = fmaxf((v0.z - m0.z) * i0.z, 0.f); z[3] = fmaxf((v0.w - m0.w) * i0.w, 0.f);
      z[4] = fmaxf((v1.x - m1.x) * i1.x, 0.f); z[5] = fmaxf((v1.y - m1.y) * i1.y, 0.f);
      z[6] = fmaxf((v1.z - m1.z) * i1.z, 0.f); z[7] = fmaxf((v1.w - m1.w) * i1.w, 0.f);
      bf16x8 a;
#pragma unroll
      for (int j = 0; j < 8; ++j) a[j] = (short)f2bf(z[j]);
      af[m] = a;
    }
#pragma unroll
    for (int n = 0; n < 4; ++n)
      bf[n] = *(const bf16x8*)(Wmb + (size_t)(wc + n * 16 + fr) * 128 + ko);
#pragma unroll
    for (int m = 0; m < 4; ++m)
#pragma unroll
      for (int n = 0; n < 4; ++n)
        acc[m][n] = __builtin_amdgcn_mfma_f32_16x16x32_bf16(af[m], bf[n], acc[m][n], 0, 0, 0);
  }

  float bcol[4];
#pragma unroll
  for (int n = 0; n < 4; ++n) bcol[n] = bm[wc + n * 16 + fr];
#pragma unroll
  for (int m = 0; m < 4; ++m) {
    const int r0 = nb + wr + m * 16 + fq * 4;
#pragma unroll
    for (int r = 0; r < 4; ++r) {
      const int gr = r0 + r;
      if (gr < N) {
#pragma unroll
        for (int n = 0; n < 4; ++n) {
          const int c = wc + n * 16 + fr;
          out[(size_t)gr * 128 + c] = acc[m][n][r] + bcol[n] + x[(size_t)gr * 128 + c];
        }
      }
    }
  }
}

extern "C" void kernel_launch(void* const* d_in, const int* in_sizes, int n_in,
                              void* d_out, int out_size, void* d_ws, size_t ws_size,
                              hipStream_t stream) {
  const float* x    = (const float*)d_in[0];
  const int*   ei   = (const int*)d_in[1];
  const float* eatt = (const float*)d_in[2];
  const float* Wq = (const float*)d_in[3];  const float* bq = (const float*)d_in[4];
  const float* Wk = (const float*)d_in[5];  const float* bk = (const float*)d_in[6];
  const float* Wv = (const float*)d_in[7];  const float* bv = (const float*)d_in[8];
  const float* We = (const float*)d_in[9];
  const float* Wsk = (const float*)d_in[10]; const float* bsk = (const float*)d_in[11];
  const float* Wp = (const float*)d_in[12]; const float* bp = (const float*)d_in[13];
  const float* Wm = (const float*)d_in[14]; const float* bm = (const float*)d_in[15];
  float* out = (float*)d_out;

  const int N = in_sizes[0] / 128;
  const int E = in_sizes[1] / 2;

  char* w = (char*)d_ws;
  auto alloc = [&](size_t bytes) {
    char* p = w;
    w += (bytes + 255) & ~(size_t)255;
    return p;
  };
  const size_t node_f = (size_t)N * 128 * sizeof(float);
  float*  t1   = (float*)alloc(node_f);
  ushort* xb16 = (ushort*)alloc((size_t)N * 128 * sizeof(ushort));
  ushort* skipb= (ushort*)alloc((size_t)N * 128 * sizeof(ushort));
  ushort* qb   = (ushort*)alloc((size_t)N * 128 * sizeof(ushort));
  ushort* wsb  = (ushort*)alloc((size_t)N * 128 * sizeof(ushort));
  ushort* kvi  = (ushort*)alloc((size_t)N * 256 * sizeof(ushort));
  ushort* u    = (ushort*)alloc((size_t)N * 512 * sizeof(ushort));
  ushort* aggS = (ushort*)alloc((size_t)N * 512 * sizeof(ushort));
  ushort* WeB  = (ushort*)alloc(128 * 512 * sizeof(ushort));
  ushort* Wb   = (ushort*)alloc(4 * 128 * 128 * sizeof(ushort));
  ushort* Mtb  = (ushort*)alloc(512 * 128 * sizeof(ushort));
  ushort* Wpb  = (ushort*)alloc(128 * 128 * sizeof(ushort));
  ushort* Wmb  = (ushort*)alloc(128 * 128 * sizeof(ushort));
  float*  bu   = (float*)alloc(512 * sizeof(float));
  int*    offs = (int*)alloc((size_t)N * sizeof(int));
  int*    curs = (int*)alloc((size_t)N * sizeof(int));
  int2*   csr  = (int2*)alloc((size_t)E * sizeof(int2));
  float*  mu    = (float*)alloc(128 * sizeof(float));
  float*  inv   = (float*)alloc(128 * sizeof(float));
  // contiguous zeroed region: deg[N] | gcnt | sums[128] | sumsq[128]
  char*   zp   = alloc((size_t)N * 4 + 1536);
  int*    deg  = (int*)zp;
  int*    gcnt = (int*)(zp + (size_t)N * 4);
  float*  sums = (float*)(zp + (size_t)N * 4 + 256);
  float*  sumsq= sums + 128;
  (void)ws_size; (void)n_in; (void)out_size;

  const int NB = (N + 127) / 128;
  const int EB = (E + 255) / 256;

  hipMemsetAsync(zp, 0, (size_t)N * 4 + 1536, stream);

  // prep: x -> bf16; all weight preps in one launch
  x2bf_kernel<<<(N * 32 + 255) / 256, 256, 0, stream>>>(x, xb16, N * 32);
  prep_all_kernel<<<(213504 + 255) / 256, 256, 0, stream>>>(Wk, Wv, Wsk, Wq, Wp, Wm, We, bq,
                                                            Wb, Wpb, Wmb, WeB, Mtb, bu);

  // projections: direct-from-global bf16 MFMA, 8 parallel y-slices
  proj_direct_kernel<<<dim3(NB, 8), 256, 0, stream>>>(xb16, Wb, Mtb, bk, bv, bsk, bq, bu,
                                                      skipb, kvi, u, qb, N);

  // CSR by dst
  deg_kernel<<<EB, 256, 0, stream>>>(ei, deg, E);
  start_kernel<<<(N + 255) / 256, 256, 0, stream>>>(deg, offs, curs, gcnt, N);
  fill_kernel<<<EB, 256, 0, stream>>>(ei, curs, csr, E);

  // fused attention: scores + softmax + aggregation (register-diet, 4096 blocks)
  fused_attn2_kernel<<<4096, 256, 0, stream>>>(csr, offs, deg, qb, kvi, u, eatt,
                                               aggS, wsb, N);

  // fused post: agg GEMM + residual + relu + Wp GEMM + LN stats
  fused_post_kernel<<<NB, 256, 0, stream>>>(aggS, WeB, wsb, skipb, Wpb, bp,
                                            t1, sums, sumsq, N);
  finalize_stats_kernel<<<1, 128, 0, stream>>>(sums, sumsq, mu, inv, N);

  // out = bf16(relu((t1-mu)*inv)) @ Wm^T + bm + x  (LN fused into A-load)
  out_gemm_kernel<<<NB, 256, 0, stream>>>(t1, mu, inv, Wmb, bm, x, out, N);
}

// Round 15
// 461.488 us; speedup vs baseline: 1.1130x; 1.1130x over previous
//
#include <hip/hip_runtime.h>
#include <stdint.h>

#define RS32 0.17677669529663687f  // 1/sqrt(32)

typedef short bf16x8 __attribute__((ext_vector_type(8)));
typedef float f32x4 __attribute__((ext_vector_type(4)));

__device__ __forceinline__ ushort f2bf(float f) {
  uint32_t b = __float_as_uint(f);
  b = (b + 0x7fffu + ((b >> 16) & 1u)) >> 16;
  return (ushort)b;
}
__device__ __forceinline__ float bflo(uint32_t w) { return __uint_as_float(w << 16); }
__device__ __forceinline__ float bfhi(uint32_t w) { return __uint_as_float(w & 0xffff0000u); }
__device__ __forceinline__ float bfu(ushort s) { return __uint_as_float(((uint32_t)s) << 16); }

// ---------------- projection: direct-from-global bf16 MFMA, zero LDS ----
// dim3(NB, 8): y=0 k(->kvi), 1 v(->kvi), 2 skip(bf16), 3 q(bf16), 4..7 u-head (W=Mtb)
__launch_bounds__(256)
__global__ void proj_direct_kernel(const ushort* __restrict__ xb16,
                                   const ushort* __restrict__ Wb,   // [4][128][128] k,v,skip,q
                                   const ushort* __restrict__ Mtb,  // [4][128][128] u heads
                                   const float* __restrict__ bk, const float* __restrict__ bv,
                                   const float* __restrict__ bs, const float* __restrict__ bq,
                                   const float* __restrict__ bu,
                                   ushort* __restrict__ skipb, ushort* __restrict__ kvi,
                                   ushort* __restrict__ u, ushort* __restrict__ qb, int N)
{
  const int y = blockIdx.y;
  const ushort* Wsrc = (y < 4) ? (Wb + (size_t)y * 16384) : (Mtb + (size_t)(y - 4) * 16384);

  const int tid = threadIdx.x;
  const int nb = blockIdx.x * 128;
  const int lane = tid & 63, wv = tid >> 6;
  const int wr = (wv >> 1) * 64, wc = (wv & 1) * 64;
  const int fr = lane & 15, fq = lane >> 4;

  f32x4 acc[4][4];
#pragma unroll
  for (int m = 0; m < 4; ++m)
#pragma unroll
    for (int n = 0; n < 4; ++n) acc[m][n] = (f32x4)0.0f;

#pragma unroll
  for (int kk = 0; kk < 4; ++kk) {
    const int ko = kk * 32 + fq * 8;
    bf16x8 af[4], bf[4];
#pragma unroll
    for (int m = 0; m < 4; ++m)
      af[m] = *(const bf16x8*)(xb16 + (size_t)(nb + wr + m * 16 + fr) * 128 + ko);
#pragma unroll
    for (int n = 0; n < 4; ++n)
      bf[n] = *(const bf16x8*)(Wsrc + (size_t)(wc + n * 16 + fr) * 128 + ko);
#pragma unroll
    for (int m = 0; m < 4; ++m)
#pragma unroll
      for (int n = 0; n < 4; ++n)
        acc[m][n] = __builtin_amdgcn_mfma_f32_16x16x32_bf16(af[m], bf[n], acc[m][n], 0, 0, 0);
  }

  float bcol[4];
#pragma unroll
  for (int n = 0; n < 4; ++n) {
    const int c = wc + n * 16 + fr;
    bcol[n] = (y == 0) ? bk[c] : (y == 1) ? bv[c] : (y == 2) ? bs[c]
            : (y == 3) ? bq[c] : bu[(y - 4) * 128 + c];
  }
#pragma unroll
  for (int m = 0; m < 4; ++m) {
    const int r0 = nb + wr + m * 16 + fq * 4;
#pragma unroll
    for (int r = 0; r < 4; ++r) {
      const int gr = r0 + r;
      if (gr < N) {
#pragma unroll
        for (int n = 0; n < 4; ++n) {
          const int c = wc + n * 16 + fr;
          float o = acc[m][n][r] + bcol[n];
          if (y == 2)      skipb[(size_t)gr * 128 + c] = f2bf(o);
          else if (y == 3) qb[(size_t)gr * 128 + c] = f2bf(o);
          else if (y == 0) kvi[(size_t)gr * 256 + (c >> 2) * 8 + (c & 3)] = f2bf(o);
          else if (y == 1) kvi[(size_t)gr * 256 + (c >> 2) * 8 + 4 + (c & 3)] = f2bf(o);
          else             u[(size_t)gr * 512 + (y - 4) * 128 + c] = f2bf(o);
        }
      }
    }
  }
}

// ---------------- prep: x -> bf16 ----------------
__global__ void x2bf_kernel(const float* __restrict__ x, ushort* __restrict__ xb, int total4)
{
  int i = blockIdx.x * 256 + threadIdx.x;
  if (i < total4) {
    float4 v = ((const float4*)x)[i];
    uint2 w = make_uint2((uint32_t)f2bf(v.x) | ((uint32_t)f2bf(v.y) << 16),
                         (uint32_t)f2bf(v.z) | ((uint32_t)f2bf(v.w) << 16));
    ((uint2*)xb)[i] = w;
  }
}

// ---------------- all weight preps in one launch (segmented grid) ----------------
__global__ void prep_all_kernel(const float* __restrict__ Wk, const float* __restrict__ Wv,
                                const float* __restrict__ Ws, const float* __restrict__ Wq,
                                const float* __restrict__ Wp, const float* __restrict__ Wm,
                                const float* __restrict__ We, const float* __restrict__ bq,
                                ushort* __restrict__ Wb, ushort* __restrict__ Wpb,
                                ushort* __restrict__ Wmb, ushort* __restrict__ WeB,
                                ushort* __restrict__ Mtb, float* __restrict__ bu)
{
  int i = blockIdx.x * 256 + threadIdx.x;
  if (i < 65536) {
    int y = i >> 14, r = i & 16383;
    const float* src = (y == 0) ? Wk : (y == 1) ? Wv : (y == 2) ? Ws : Wq;
    Wb[i] = f2bf(src[r]);
    return;
  }
  i -= 65536;
  if (i < 16384) { Wpb[i] = f2bf(Wp[i]); Wmb[i] = f2bf(Wm[i]); return; }
  i -= 16384;
  if (i < 65536) {
    int c = i >> 9, j = i & 511;
    int hh = j >> 7, k2 = j & 127;
    WeB[i] = (hh == (c >> 5)) ? f2bf(We[(size_t)c * 128 + k2]) : (ushort)0;
    return;
  }
  i -= 65536;
  if (i < 65536) {
    int jp = i >> 7, d = i & 127;
    int h = jp >> 7, j = jp & 127;
    const float* wq = Wq + (size_t)(32 * h) * 128 + d;
    const float* we = We + (size_t)(32 * h) * 128 + j;
    float acc = 0.f;
#pragma unroll 8
    for (int a = 0; a < 32; ++a) acc = fmaf(wq[a * 128], we[a * 128], acc);
    Mtb[i] = f2bf(acc);
    return;
  }
  i -= 65536;
  if (i < 512) {
    int h = i >> 7, j = i & 127;
    float acc = 0.f;
    for (int a = 0; a < 32; ++a)
      acc = fmaf(bq[32 * h + a], We[(size_t)(32 * h + a) * 128 + j], acc);
    bu[i] = acc;
  }
}

// ---------------- CSR build ----------------
__global__ void deg_kernel(const int* __restrict__ ei, int* __restrict__ deg, int E)
{
  int e = blockIdx.x * 256 + threadIdx.x;
  if (e < E) atomicAdd(&deg[ei[E + e]], 1);
}

__launch_bounds__(256)
__global__ void start_kernel(const int* __restrict__ deg, int* __restrict__ offs,
                             int* __restrict__ cursor, int* __restrict__ gcount, int N)
{
  const int i = blockIdx.x * 256 + threadIdx.x;
  const int lane = threadIdx.x & 63;
  int d = (i < N) ? deg[i] : 0;
  int scan = d;
#pragma unroll
  for (int ofs = 1; ofs < 64; ofs <<= 1) {
    int t = __shfl_up(scan, ofs, 64);
    if (lane >= ofs) scan += t;
  }
  int total = __shfl(scan, 63, 64);
  int base = 0;
  if (lane == 63) base = atomicAdd(gcount, total);
  base = __shfl(base, 63, 64);
  int excl = base + scan - d;
  if (i < N) { offs[i] = excl; cursor[i] = excl; }
}

__global__ void fill_kernel(const int* __restrict__ ei, int* __restrict__ cursor,
                            int2* __restrict__ csr, int E)
{
  int e = blockIdx.x * 256 + threadIdx.x;
  if (e < E) {
    int dst = ei[E + e];
    int slot = atomicAdd(&cursor[dst], 1);
    csr[slot] = make_int2(ei[e], e);
  }
}

// ---------------- fused node-major attention (R13 config: explicit depth-1 prefetch) ----------------
// wave per node; 2 edge slots of 32 lanes; lane (p, j32) owns channels 4*j32..+3 (head j32>>3).
// Explicit prefetch rotation is load-bearing (R14 A/B: removing it cost +55us despite +9% occupancy).
__launch_bounds__(256)
__global__ void fused_attn2_kernel(const int2* __restrict__ csr, const int* __restrict__ offs,
                                   const int* __restrict__ deg,
                                   const ushort* __restrict__ qb, const ushort* __restrict__ kvi,
                                   const ushort* __restrict__ u,
                                   const float* __restrict__ eattr,
                                   ushort* __restrict__ aggS, ushort* __restrict__ wsb, int N)
{
  const int tid = threadIdx.x;
  const int lane = tid & 63;
  const int wid = tid >> 6;
  const int p = lane >> 5;          // edge slot 0/1
  const int j32 = lane & 31;
  const int c0 = j32 * 4;           // my 4 channels
  const int h = j32 >> 3;           // head of my channels
  const int gwave = blockIdx.x * 4 + wid;
  const int nwaves = gridDim.x * 4;

  for (int n = gwave; n < N; n += nwaves) {
    const int e0 = offs[n];
    const int e1 = e0 + deg[n];

    const uint2 qp = *(const uint2*)(qb + (size_t)n * 128 + c0);
    uint2 uhp[4];
#pragma unroll
    for (int hh = 0; hh < 4; ++hh)
      uhp[hh] = *(const uint2*)(u + (size_t)n * 512 + hh * 128 + c0);

    float ws0 = 0.f, ws1 = 0.f, ws2 = 0.f, ws3 = 0.f;
    float ax[4][4];
#pragma unroll
    for (int hh = 0; hh < 4; ++hh)
#pragma unroll
      for (int j = 0; j < 4; ++j) ax[hh][j] = 0.f;
    float sm0 = 0.f, sm1 = 0.f, sm2 = 0.f, sm3 = 0.f;

    int sl = e0 + p;
    if (sl < e1) {
      int2 seC = csr[sl];
      float4 eaC = *(const float4*)(eattr + (size_t)seC.y * 128 + c0);
      uint4 kvC = *(const uint4*)(kvi + (size_t)seC.x * 256 + j32 * 8);
      int sln = sl + 2;
      int2 seN = (sln < e1) ? csr[sln] : seC;
      for (; sl < e1; sl += 2) {
        float4 eaN = *(const float4*)(eattr + (size_t)seN.y * 128 + c0);
        uint4 kvN = *(const uint4*)(kvi + (size_t)seN.x * 256 + j32 * 8);
        const int slf = sl + 4;
        int2 seF = (slf < e1) ? csr[slf] : seN;

        float P0 = eaC.x * bflo(uhp[0].x) + eaC.y * bfhi(uhp[0].x)
                 + eaC.z * bflo(uhp[0].y) + eaC.w * bfhi(uhp[0].y);
        float P1 = eaC.x * bflo(uhp[1].x) + eaC.y * bfhi(uhp[1].x)
                 + eaC.z * bflo(uhp[1].y) + eaC.w * bfhi(uhp[1].y);
        float P2 = eaC.x * bflo(uhp[2].x) + eaC.y * bfhi(uhp[2].x)
                 + eaC.z * bflo(uhp[2].y) + eaC.w * bfhi(uhp[2].y);
        float P3 = eaC.x * bflo(uhp[3].x) + eaC.y * bfhi(uhp[3].x)
                 + eaC.z * bflo(uhp[3].y) + eaC.w * bfhi(uhp[3].y);
        const float qk = bflo(qp.x) * bflo(kvC.x) + bfhi(qp.x) * bfhi(kvC.x)
                       + bflo(qp.y) * bflo(kvC.y) + bfhi(qp.y) * bfhi(kvC.y);
        P0 += (h == 0) ? qk : 0.f;
        P1 += (h == 1) ? qk : 0.f;
        P2 += (h == 2) ? qk : 0.f;
        P3 += (h == 3) ? qk : 0.f;
#pragma unroll
        for (int mm = 1; mm <= 16; mm <<= 1) {
          P0 += __shfl_xor(P0, mm, 64);
          P1 += __shfl_xor(P1, mm, 64);
          P2 += __shfl_xor(P2, mm, 64);
          P3 += __shfl_xor(P3, mm, 64);
        }
        const float a0 = __expf(P0 * RS32);
        const float a1 = __expf(P1 * RS32);
        const float a2 = __expf(P2 * RS32);
        const float a3 = __expf(P3 * RS32);
        sm0 += a0; sm1 += a1; sm2 += a2; sm3 += a3;
        const float aV = (h == 0) ? a0 : (h == 1) ? a1 : (h == 2) ? a2 : a3;
        ws0 = fmaf(aV, bflo(kvC.z), ws0); ws1 = fmaf(aV, bfhi(kvC.z), ws1);
        ws2 = fmaf(aV, bflo(kvC.w), ws2); ws3 = fmaf(aV, bfhi(kvC.w), ws3);
        ax[0][0] = fmaf(a0, eaC.x, ax[0][0]); ax[0][1] = fmaf(a0, eaC.y, ax[0][1]);
        ax[0][2] = fmaf(a0, eaC.z, ax[0][2]); ax[0][3] = fmaf(a0, eaC.w, ax[0][3]);
        ax[1][0] = fmaf(a1, eaC.x, ax[1][0]); ax[1][1] = fmaf(a1, eaC.y, ax[1][1]);
        ax[1][2] = fmaf(a1, eaC.z, ax[1][2]); ax[1][3] = fmaf(a1, eaC.w, ax[1][3]);
        ax[2][0] = fmaf(a2, eaC.x, ax[2][0]); ax[2][1] = fmaf(a2, eaC.y, ax[2][1]);
        ax[2][2] = fmaf(a2, eaC.z, ax[2][2]); ax[2][3] = fmaf(a2, eaC.w, ax[2][3]);
        ax[3][0] = fmaf(a3, eaC.x, ax[3][0]); ax[3][1] = fmaf(a3, eaC.y, ax[3][1]);
        ax[3][2] = fmaf(a3, eaC.z, ax[3][2]); ax[3][3] = fmaf(a3, eaC.w, ax[3][3]);

        eaC = eaN; kvC = kvN; seN = seF;
      }
    }

#pragma unroll
    for (int hh = 0; hh < 4; ++hh)
#pragma unroll
      for (int j = 0; j < 4; ++j) ax[hh][j] += __shfl_xor(ax[hh][j], 32, 64);
    ws0 += __shfl_xor(ws0, 32, 64); ws1 += __shfl_xor(ws1, 32, 64);
    ws2 += __shfl_xor(ws2, 32, 64); ws3 += __shfl_xor(ws3, 32, 64);
    sm0 += __shfl_xor(sm0, 32, 64); sm1 += __shfl_xor(sm1, 32, 64);
    sm2 += __shfl_xor(sm2, 32, 64); sm3 += __shfl_xor(sm3, 32, 64);

    const float iv0 = (sm0 > 0.f) ? 1.f / sm0 : 0.f;
    const float iv1 = (sm1 > 0.f) ? 1.f / sm1 : 0.f;
    const float iv2 = (sm2 > 0.f) ? 1.f / sm2 : 0.f;
    const float iv3 = (sm3 > 0.f) ? 1.f / sm3 : 0.f;

    if (p == 0) {
      const float s = (h == 0) ? iv0 : (h == 1) ? iv1 : (h == 2) ? iv2 : iv3;
      uint2 w = make_uint2(((uint32_t)f2bf(ws0 * s)) | (((uint32_t)f2bf(ws1 * s)) << 16),
                           ((uint32_t)f2bf(ws2 * s)) | (((uint32_t)f2bf(ws3 * s)) << 16));
      *(uint2*)(wsb + (size_t)n * 128 + c0) = w;
    }

    float o0[4], o1[4], s0, s1;
    if (p == 0) {
#pragma unroll
      for (int j = 0; j < 4; ++j) { o0[j] = ax[0][j]; o1[j] = ax[1][j]; }
      s0 = iv0; s1 = iv1;
    } else {
#pragma unroll
      for (int j = 0; j < 4; ++j) { o0[j] = ax[2][j]; o1[j] = ax[3][j]; }
      s0 = iv2; s1 = iv3;
    }
    uint2 w0 = make_uint2(((uint32_t)f2bf(o0[0] * s0)) | (((uint32_t)f2bf(o0[1] * s0)) << 16),
                          ((uint32_t)f2bf(o0[2] * s0)) | (((uint32_t)f2bf(o0[3] * s0)) << 16));
    uint2 w1 = make_uint2(((uint32_t)f2bf(o1[0] * s1)) | (((uint32_t)f2bf(o1[1] * s1)) << 16),
                          ((uint32_t)f2bf(o1[2] * s1)) | (((uint32_t)f2bf(o1[3] * s1)) << 16));
    *(uint2*)(aggS + (size_t)n * 512 + (p * 2) * 128 + c0) = w0;
    *(uint2*)(aggS + (size_t)n * 512 + (p * 2 + 1) * 128 + c0) = w1;
  }
}

// ---------------- fused post: attn = aggS@WeB^T + wsb; z = bf16(relu(attn+skip));
// t1 = z @ Wpb^T + bp; fused LN column stats ----------------
__launch_bounds__(256)
__global__ void fused_post_kernel(const ushort* __restrict__ aggS, const ushort* __restrict__ WeB,
                                  const ushort* __restrict__ wsb, const ushort* __restrict__ skipb,
                                  const ushort* __restrict__ Wpb, const float* __restrict__ bp,
                                  float* __restrict__ t1,
                                  float* __restrict__ sums, float* __restrict__ sumsq, int N)
{
  __shared__ ushort smem[2 * 128 * 72];   // phase1: As|Bs ; phase2: zs[128][136]
  ushort* As = smem;
  ushort* Bs = smem + 128 * 72;
  const int tid = threadIdx.x;
  const int nb = blockIdx.x * 128;
  const int lane = tid & 63, wv = tid >> 6;
  const int wr = (wv >> 1) * 64, wc = (wv & 1) * 64;
  const int fr = lane & 15, fq = lane >> 4;
  const int r = tid >> 1, cs = (tid & 1) * 32;

  f32x4 acc[4][4];
#pragma unroll
  for (int m = 0; m < 4; ++m)
#pragma unroll
    for (int n = 0; n < 4; ++n) acc[m][n] = (f32x4)0.0f;

  // phase 1: aggS @ WeB^T (K=512)
  for (int kc = 0; kc < 512; kc += 64) {
    uint4 av[4], bv[4];
    if (nb + r < N) {
      const uint4* src = (const uint4*)(aggS + (size_t)(nb + r) * 512 + kc + cs);
      av[0] = src[0]; av[1] = src[1]; av[2] = src[2]; av[3] = src[3];
    } else {
#pragma unroll
      for (int i = 0; i < 4; ++i) av[i] = make_uint4(0, 0, 0, 0);
    }
    {
      const uint4* src = (const uint4*)(WeB + (size_t)r * 512 + kc + cs);
      bv[0] = src[0]; bv[1] = src[1]; bv[2] = src[2]; bv[3] = src[3];
    }
    if (kc) __syncthreads();
#pragma unroll
    for (int i = 0; i < 4; ++i) {
      *(uint4*)&As[r * 72 + cs + i * 8] = av[i];
      *(uint4*)&Bs[r * 72 + cs + i * 8] = bv[i];
    }
    __syncthreads();

#pragma unroll
    for (int s = 0; s < 2; ++s) {
      bf16x8 ah[4], bh[4];
#pragma unroll
      for (int m = 0; m < 4; ++m)
        ah[m] = *(const bf16x8*)&As[(wr + m * 16 + fr) * 72 + s * 32 + fq * 8];
#pragma unroll
      for (int n = 0; n < 4; ++n)
        bh[n] = *(const bf16x8*)&Bs[(wc + n * 16 + fr) * 72 + s * 32 + fq * 8];
#pragma unroll
      for (int m = 0; m < 4; ++m)
#pragma unroll
        for (int n = 0; n < 4; ++n)
          acc[m][n] = __builtin_amdgcn_mfma_f32_16x16x32_bf16(ah[m], bh[n], acc[m][n], 0, 0, 0);
    }
  }
  __syncthreads();   // all waves done reading As/Bs

  // epilogue 1: z = bf16(relu(attn + ws + skip)) -> zs (aliased over smem)
  ushort* zs = smem;   // [128][136]
#pragma unroll
  for (int m = 0; m < 4; ++m) {
    const int lr0 = wr + m * 16 + fq * 4;
#pragma unroll
    for (int rr = 0; rr < 4; ++rr) {
      const int lrow = lr0 + rr;
      const int gr = nb + lrow;
#pragma unroll
      for (int n = 0; n < 4; ++n) {
        const int c = wc + n * 16 + fr;
        float o = 0.f;
        if (gr < N) {
          o = acc[m][n][rr] + bfu(wsb[(size_t)gr * 128 + c]) + bfu(skipb[(size_t)gr * 128 + c]);
          o = fmaxf(o, 0.f);
        }
        zs[lrow * 136 + c] = f2bf(o);
      }
    }
  }
  __syncthreads();

  // phase 2: t1 = zs @ Wpb^T (K=128), Wpb direct from global
  f32x4 acc2[4][4];
#pragma unroll
  for (int m = 0; m < 4; ++m)
#pragma unroll
    for (int n = 0; n < 4; ++n) acc2[m][n] = (f32x4)0.0f;
#pragma unroll
  for (int kk = 0; kk < 4; ++kk) {
    const int ko = kk * 32 + fq * 8;
    bf16x8 af[4], bf[4];
#pragma unroll
    for (int m = 0; m < 4; ++m)
      af[m] = *(const bf16x8*)&zs[(wr + m * 16 + fr) * 136 + ko];
#pragma unroll
    for (int n = 0; n < 4; ++n)
      bf[n] = *(const bf16x8*)(Wpb + (size_t)(wc + n * 16 + fr) * 128 + ko);
#pragma unroll
    for (int m = 0; m < 4; ++m)
#pragma unroll
      for (int n = 0; n < 4; ++n)
        acc2[m][n] = __builtin_amdgcn_mfma_f32_16x16x32_bf16(af[m], bf[n], acc2[m][n], 0, 0, 0);
  }

  float bcol[4];
#pragma unroll
  for (int n = 0; n < 4; ++n) bcol[n] = bp[wc + n * 16 + fr];
  float csum[4] = {0.f, 0.f, 0.f, 0.f}, csum2[4] = {0.f, 0.f, 0.f, 0.f};
#pragma unroll
  for (int m = 0; m < 4; ++m) {
    const int r0 = nb + wr + m * 16 + fq * 4;
#pragma unroll
    for (int rr = 0; rr < 4; ++rr) {
      const int gr = r0 + rr;
      if (gr < N) {
#pragma unroll
        for (int n = 0; n < 4; ++n) {
          const int c = wc + n * 16 + fr;
          float o = acc2[m][n][rr] + bcol[n];
          t1[(size_t)gr * 128 + c] = o;
          csum[n] += o; csum2[n] = fmaf(o, o, csum2[n]);
        }
      }
    }
  }
#pragma unroll
  for (int n = 0; n < 4; ++n) {
    csum[n] += __shfl_xor(csum[n], 16, 64);
    csum[n] += __shfl_xor(csum[n], 32, 64);
    csum2[n] += __shfl_xor(csum2[n], 16, 64);
    csum2[n] += __shfl_xor(csum2[n], 32, 64);
  }
  if (fq == 0) {
#pragma unroll
    for (int n = 0; n < 4; ++n) {
      atomicAdd(&sums[wc + n * 16 + fr], csum[n]);
      atomicAdd(&sumsq[wc + n * 16 + fr], csum2[n]);
    }
  }
}

__global__ void finalize_stats_kernel(const float* __restrict__ sums, const float* __restrict__ sumsq,
                                      float* __restrict__ mu, float* __restrict__ inv, int N)
{
  int c = threadIdx.x;
  float m = sums[c] / (float)N;
  float var = sumsq[c] / (float)N - m * m;
  float sd = sqrtf(fmaxf(var, 0.f));
  mu[c] = m;
  inv[c] = 1.f / (sd + 1e-5f);
}

// ---------------- out = bf16(relu((t1-mu)*inv)) @ Wmb^T + bm + x  (LN fused into A-load) ----
__launch_bounds__(256)
__global__ void out_gemm_kernel(const float* __restrict__ t1, const float* __restrict__ mu,
                                const float* __restrict__ inv,
                                const ushort* __restrict__ Wmb,
                                const float* __restrict__ bm, const float* __restrict__ x,
                                float* __restrict__ out, int N)
{
  const int tid = threadIdx.x;
  const int nb = blockIdx.x * 128;
  const int lane = tid & 63, wv = tid >> 6;
  const int wr = (wv >> 1) * 64, wc = (wv & 1) * 64;
  const int fr = lane & 15, fq = lane >> 4;

  f32x4 acc[4][4];
#pragma unroll
  for (int m = 0; m < 4; ++m)
#pragma unroll
    for (int n = 0; n < 4; ++n) acc[m][n] = (f32x4)0.0f;

#pragma unroll
  for (int kk = 0; kk < 4; ++kk) {
    const int ko = kk * 32 + fq * 8;
    const float4 m0 = *(const float4*)(mu + ko);
    const float4 m1 = *(const float4*)(mu + ko + 4);
    const float4 i0 = *(const float4*)(inv + ko);
    const float4 i1 = *(const float4*)(inv + ko + 4);
    bf16x8 af[4], bf[4];
#pragma unroll
    for (int m = 0; m < 4; ++m) {
      const int gr = nb + wr + m * 16 + fr;
      float4 v0 = make_float4(0.f, 0.f, 0.f, 0.f), v1 = v0;
      if (gr < N) {
        v0 = *(const float4*)(t1 + (size_t)gr * 128 + ko);
        v1 = *(const float4*)(t1 + (size_t)gr * 128 + ko + 4);
      }
      float z[8];
      z[0] = fmaxf((v0.x - m0.x) * i0.x, 0.f); z[1] = fmaxf((v0.y - m0.y) * i0.y, 0.f);
      z[2] = fmaxf((v0.z - m0.z) * i0.z, 0.f); z[3] = fmaxf((v0.w - m0.w) * i0.w, 0.f);
      z[4] = fmaxf((v1.x - m1.x) * i1.x, 0.f); z[5] = fmaxf((v1.y - m1.y) * i1.y, 0.f);
      z[6] = fmaxf((v1.z - m1.z) * i1.z, 0.f); z[7] = fmaxf((v1.w - m1.w) * i1.w, 0.f);
      bf16x8 a;
#pragma unroll
      for (int j = 0; j < 8; ++j) a[j] = (short)f2bf(z[j]);
      af[m] = a;
    }
#pragma unroll
    for (int n = 0; n < 4; ++n)
      bf[n] = *(const bf16x8*)(Wmb + (size_t)(wc + n * 16 + fr) * 128 + ko);
#pragma unroll
    for (int m = 0; m < 4; ++m)
#pragma unroll
      for (int n = 0; n < 4; ++n)
        acc[m][n] = __builtin_amdgcn_mfma_f32_16x16x32_bf16(af[m], bf[n], acc[m][n], 0, 0, 0);
  }

  float bcol[4];
#pragma unroll
  for (int n = 0; n < 4; ++n) bcol[n] = bm[wc + n * 16 + fr];
#pragma unroll
  for (int m = 0; m < 4; ++m) {
    const int r0 = nb + wr + m * 16 + fq * 4;
#pragma unroll
    for (int r = 0; r < 4; ++r) {
      const int gr = r0 + r;
      if (gr < N) {
#pragma unroll
        for (int n = 0; n < 4; ++n) {
          const int c = wc + n * 16 + fr;
          out[(size_t)gr * 128 + c] = acc[m][n][r] + bcol[n] + x[(size_t)gr * 128 + c];
        }
      }
    }
  }
}

extern "C" void kernel_launch(void* const* d_in, const int* in_sizes, int n_in,
                              void* d_out, int out_size, void* d_ws, size_t ws_size,
                              hipStream_t stream) {
  const float* x    = (const float*)d_in[0];
  const int*   ei   = (const int*)d_in[1];
  const float* eatt = (const float*)d_in[2];
  const float* Wq = (const float*)d_in[3];  const float* bq = (const float*)d_in[4];
  const float* Wk = (const float*)d_in[5];  const float* bk = (const float*)d_in[6];
  const float* Wv = (const float*)d_in[7];  const float* bv = (const float*)d_in[8];
  const float* We = (const float*)d_in[9];
  const float* Wsk = (const float*)d_in[10]; const float* bsk = (const float*)d_in[11];
  const float* Wp = (const float*)d_in[12]; const float* bp = (const float*)d_in[13];
  const float* Wm = (const float*)d_in[14]; const float* bm = (const float*)d_in[15];
  float* out = (float*)d_out;

  const int N = in_sizes[0] / 128;
  const int E = in_sizes[1] / 2;

  char* w = (char*)d_ws;
  auto alloc = [&](size_t bytes) {
    char* p = w;
    w += (bytes + 255) & ~(size_t)255;
    return p;
  };
  const size_t node_f = (size_t)N * 128 * sizeof(float);
  float*  t1   = (float*)alloc(node_f);
  ushort* xb16 = (ushort*)alloc((size_t)N * 128 * sizeof(ushort));
  ushort* skipb= (ushort*)alloc((size_t)N * 128 * sizeof(ushort));
  ushort* qb   = (ushort*)alloc((size_t)N * 128 * sizeof(ushort));
  ushort* wsb  = (ushort*)alloc((size_t)N * 128 * sizeof(ushort));
  ushort* kvi  = (ushort*)alloc((size_t)N * 256 * sizeof(ushort));
  ushort* u    = (ushort*)alloc((size_t)N * 512 * sizeof(ushort));
  ushort* aggS = (ushort*)alloc((size_t)N * 512 * sizeof(ushort));
  ushort* WeB  = (ushort*)alloc(128 * 512 * sizeof(ushort));
  ushort* Wb   = (ushort*)alloc(4 * 128 * 128 * sizeof(ushort));
  ushort* Mtb  = (ushort*)alloc(512 * 128 * sizeof(ushort));
  ushort* Wpb  = (ushort*)alloc(128 * 128 * sizeof(ushort));
  ushort* Wmb  = (ushort*)alloc(128 * 128 * sizeof(ushort));
  float*  bu   = (float*)alloc(512 * sizeof(float));
  int*    offs = (int*)alloc((size_t)N * sizeof(int));
  int*    curs = (int*)alloc((size_t)N * sizeof(int));
  int2*   csr  = (int2*)alloc((size_t)E * sizeof(int2));
  float*  mu    = (float*)alloc(128 * sizeof(float));
  float*  inv   = (float*)alloc(128 * sizeof(float));
  // contiguous zeroed region: deg[N] | gcnt | sums[128] | sumsq[128]
  char*   zp   = alloc((size_t)N * 4 + 1536);
  int*    deg  = (int*)zp;
  int*    gcnt = (int*)(zp + (size_t)N * 4);
  float*  sums = (float*)(zp + (size_t)N * 4 + 256);
  float*  sumsq= sums + 128;
  (void)ws_size; (void)n_in; (void)out_size;

  const int NB = (N + 127) / 128;
  const int EB = (E + 255) / 256;

  hipMemsetAsync(zp, 0, (size_t)N * 4 + 1536, stream);

  // prep: x -> bf16; all weight preps in one launch
  x2bf_kernel<<<(N * 32 + 255) / 256, 256, 0, stream>>>(x, xb16, N * 32);
  prep_all_kernel<<<(213504 + 255) / 256, 256, 0, stream>>>(Wk, Wv, Wsk, Wq, Wp, Wm, We, bq,
                                                            Wb, Wpb, Wmb, WeB, Mtb, bu);

  // projections: direct-from-global bf16 MFMA, 8 parallel y-slices
  proj_direct_kernel<<<dim3(NB, 8), 256, 0, stream>>>(xb16, Wb, Mtb, bk, bv, bsk, bq, bu,
                                                      skipb, kvi, u, qb, N);

  // CSR by dst
  deg_kernel<<<EB, 256, 0, stream>>>(ei, deg, E);
  start_kernel<<<(N + 255) / 256, 256, 0, stream>>>(deg, offs, curs, gcnt, N);
  fill_kernel<<<EB, 256, 0, stream>>>(ei, curs, csr, E);

  // fused attention: scores + softmax + aggregation (explicit depth-1 prefetch, 2048 blocks)
  fused_attn2_kernel<<<2048, 256, 0, stream>>>(csr, offs, deg, qb, kvi, u, eatt,
                                               aggS, wsb, N);

  // fused post: agg GEMM + residual + relu + Wp GEMM + LN stats
  fused_post_kernel<<<NB, 256, 0, stream>>>(aggS, WeB, wsb, skipb, Wpb, bp,
                                            t1, sums, sumsq, N);
  finalize_stats_kernel<<<1, 128, 0, stream>>>(sums, sumsq, mu, inv, N);

  // out = bf16(relu((t1-mu)*inv)) @ Wm^T + bm + x  (LN fused into A-load)
  out_gemm_kernel<<<NB, 256, 0, stream>>>(t1, mu, inv, Wmb, bm, x, out, N);
}